// Round 10
// baseline (65.275 us; speedup 1.0000x reference)
//
#include <hip/hip_runtime.h>

#define NB 512
#define NATOMS 1024
#define NG 256
#define NL 8
#define NK 128

#define KBT 0.59616123f            // 0.0019872041 * 300
#define ALPHA_C 10.0f
#define LN2 0.6931471805599453f
#define LOG2E 1.4426950408889634f
#define INV2BW2 22.222221f         // 1/(2*0.15^2)
#define SCALE2 (INV2BW2 * LOG2E)   // log2-domain scale
#define LOG_NORM (-1.0170649f)     // log(128) + 3*log(2*pi*BW^2)

#define WL_CAP 2048                // max (g,l) pairs = NG*NL
#define FILL_BLOCKS 128            // 128*256*16B = 512 KiB = NG*NB*4B exactly

__device__ __forceinline__ float fexp2(float x) { return __builtin_amdgcn_exp2f(x); }
__device__ __forceinline__ float flog2(float x) { return __builtin_amdgcn_logf(x); }

// monotone float<->uint key (unsigned order == float order), for atomicMin
__device__ __forceinline__ unsigned fkey(float f) {
  unsigned u = __float_as_uint(f);
  return (u & 0x80000000u) ? ~u : (u | 0x80000000u);
}
__device__ __forceinline__ float funkey(unsigned k) {
  unsigned u = (k & 0x80000000u) ? (k ^ 0x80000000u) : ~k;
  return __uint_as_float(u);
}

__device__ __forceinline__ float wred_min(float v) {
#pragma unroll
  for (int m = 32; m >= 1; m >>= 1) v = fminf(v, __shfl_xor(v, m, 64));
  return v;
}
__device__ __forceinline__ float wred_sum(float v) {
#pragma unroll
  for (int m = 32; m >= 1; m >>= 1) v += __shfl_xor(v, m, 64);
  return v;
}

// Precompute the transformed KDE table for ALL 2048 (g,l) entries:
// tabG[gl][k][8] = {mu0*cf .. mu5*cf, -mu2*SCALE2, 0}.  Coalesced r/w, ~2us.
__global__ __launch_bounds__(128) void prep_tab(
    const float* __restrict__ kde, float* __restrict__ tabG) {
  const int gl = blockIdx.x;
  const int k = threadIdx.x;
  const float* mp = kde + ((size_t)gl * NK + k) * 6;
  float m0 = mp[0], m1 = mp[1], m2 = mp[2], m3 = mp[3], m4 = mp[4], m5 = mp[5];
  float mu2 = m0 * m0 + m1 * m1 + m2 * m2 + m3 * m3 + m4 * m4 + m5 * m5;
  const float cf = 2.0f * SCALE2;
  float4* dst = reinterpret_cast<float4*>(tabG + ((size_t)gl * NK + k) * 8);
  dst[0] = make_float4(m0 * cf, m1 * cf, m2 * cf, m3 * cf);
  dst[1] = make_float4(m4 * cf, m5 * cf, -mu2 * SCALE2, 0.0f);
}

// Grid = 1 + FILL_BLOCKS.  Block 0: prefix-sum nl over the 256 groups ->
// packed worklist of active (g,l) pairs (wl[WL_CAP] = count).  Blocks
// 1..FILL_BLOCKS: fill gmin_u with 0xFFFFFFFF (full 512 KiB).
__global__ __launch_bounds__(256) void build_worklist(
    const int* __restrict__ gsizes, int* __restrict__ wl,
    uint4* __restrict__ gmin_u4) {
  const int t = threadIdx.x;
  if (blockIdx.x != 0) {
    const unsigned F = 0xFFFFFFFFu;
    gmin_u4[(blockIdx.x - 1) * 256 + t] = make_uint4(F, F, F, F);
    return;
  }
  const int lane = t & 63, wid = t >> 6;
  int gs = gsizes[t];
  int nl = gs < 1 ? 1 : (gs > NL ? NL : gs);
  int x = nl;                       // inclusive scan within wave
#pragma unroll
  for (int m = 1; m < 64; m <<= 1) {
    int y = __shfl_up(x, m, 64);
    if (lane >= m) x += y;
  }
  __shared__ int wsum[4];
  if (lane == 63) wsum[wid] = x;
  __syncthreads();
  int off = 0;
  for (int i = 0; i < wid; ++i) off += wsum[i];
  int inc = off + x, exc = inc - nl;
  for (int j = 0; j < nl; ++j) wl[exc + j] = (t << 3) | j;   // entry == gl
  if (t == 255) wl[WL_CAP] = inc;   // total active pairs
}

// Block = one worklist entry; thread t owns b = t and b = t+256 (table loads
// amortized over 2 batches).  The table is read with per-lane (runtime-
// uniform) VECTOR global loads: one L2 broadcast transaction per wave,
// deep vmcnt pipelining -- bypasses the LDS-issue wall (r6: 35us), the
// low-occupancy wall (r7), and the SMEM-latency wall (r9).  gl is laundered
// through __shfl so LLVM's uniformity analysis cannot demote the loads to
// s_load.  K=128 logsumexp: 2 online chains per b, 4-k merge groups, log2.
__global__ __launch_bounds__(256) void stage1_kernel(
    const float* __restrict__ positions, const float* __restrict__ tabG,
    const float* __restrict__ weight, const float* __restrict__ offs,
    const int* __restrict__ atom_idxs, const int* __restrict__ wl,
    unsigned* __restrict__ gmin_u) {
  const int w = blockIdx.x;
  const int count = wl[WL_CAP];
  if (w >= count) return;                 // contiguous inactive tail
  const int gl = wl[w];
  const int g = gl >> 3;
  // force-divergent copy: __shfl output is a VGPR the compiler treats as
  // non-uniform -> vector global_load (HW broadcast), not s_load.
  const int glv = __shfl(gl, 0);
  const float4* tb = reinterpret_cast<const float4*>(tabG) + (size_t)glv * NK * 2;

  const int t = threadIdx.x;
  const int4 idx = *reinterpret_cast<const int4*>(atom_idxs + (gl << 2));
  const int ids[4] = {idx.x, idx.y, idx.z, idx.w};
  const int PI_[6] = {0, 0, 0, 1, 1, 2};
  const int PJ_[6] = {1, 2, 3, 2, 3, 3};

  float d[2][6], c2[2];
#pragma unroll
  for (int h = 0; h < 2; ++h) {
    const int b = (h << 8) + t;
    const float* pb = positions + (size_t)b * NATOMS * 3;
    float ax[4], ay[4], az[4];
#pragma unroll
    for (int j = 0; j < 4; ++j) {
      const float3 p = *reinterpret_cast<const float3*>(pb + ids[j] * 3);
      ax[j] = p.x; ay[j] = p.y; az[j] = p.z;
    }
    float x2 = 0.0f;
#pragma unroll
    for (int q = 0; q < 6; ++q) {
      float dx = ax[PI_[q]] - ax[PJ_[q]];
      float dy = ay[PI_[q]] - ay[PJ_[q]];
      float dz = az[PI_[q]] - az[PJ_[q]];
      float dd = dx * dx + dy * dy + dz * dz + 1e-12f;
      d[h][q] = sqrtf(dd);
      x2 += d[h][q] * d[h][q];
    }
    c2[h] = -x2 * SCALE2;               // constant over k (log2 domain)
  }

  // online LSE over K: 2 chains per b (chain = tile parity), 4-k tiles.
  float m_[2][2] = {{-1e30f, -1e30f}, {-1e30f, -1e30f}};
  float s_[2][2] = {{0.0f, 0.0f}, {0.0f, 0.0f}};
#pragma unroll 4
  for (int kt = 0; kt < NK / 4; ++kt) {
    const int k0 = kt << 2;
    const int ch = kt & 1;
    float4 A[4], Bv[4];
#pragma unroll
    for (int i = 0; i < 4; ++i) {
      A[i]  = tb[(k0 + i) * 2];
      Bv[i] = tb[(k0 + i) * 2 + 1];
    }
#pragma unroll
    for (int h = 0; h < 2; ++h) {
      float v[4];
#pragma unroll
      for (int i = 0; i < 4; ++i) {
        float vv = Bv[i].z;
        vv = fmaf(A[i].x, d[h][0], vv);
        vv = fmaf(A[i].y, d[h][1], vv);
        vv = fmaf(A[i].z, d[h][2], vv);
        vv = fmaf(A[i].w, d[h][3], vv);
        vv = fmaf(Bv[i].x, d[h][4], vv);
        vv = fmaf(Bv[i].y, d[h][5], vv);
        v[i] = vv;
      }
      float gm = fmaxf(fmaxf(v[0], v[1]), fmaxf(v[2], v[3]));
      float p = fexp2(v[0] - gm) + fexp2(v[1] - gm)
              + fexp2(v[2] - gm) + fexp2(v[3] - gm);
      float nm = fmaxf(m_[h][ch], gm);
      s_[h][ch] = fmaf(s_[h][ch], fexp2(m_[h][ch] - nm), p * fexp2(gm - nm));
      m_[h][ch] = nm;
    }
  }

  const float wgt = weight[gl], off = offs[gl];
#pragma unroll
  for (int h = 0; h < 2; ++h) {
    float M = fmaxf(m_[h][0], m_[h][1]);
    float S = s_[h][0] * fexp2(m_[h][0] - M) + s_[h][1] * fexp2(m_[h][1] - M);
    float lse2 = c2[h] + M + flog2(S);       // log2(sum_k exp(v_k))
    float logP = lse2 * LN2 - LOG_NORM;
    float scaled = -KBT * logP * wgt + off;
    atomicMin(&gmin_u[g * NB + (h << 8) + t], fkey(scaled));
  }
}

// One block per b: min over g, then logsumexp(-ALPHA*gmin) over g.
__global__ __launch_bounds__(256) void stage2_kernel(
    const unsigned* __restrict__ gmin_u, float* __restrict__ out) {
  const int b = blockIdx.x;
  const int t = threadIdx.x;
  const int lane = t & 63;
  const int wid = t >> 6;
  float v = funkey(gmin_u[t * NB + b]);
  __shared__ float sm[4], ss[4];
  float m = wred_min(v);
  if (lane == 0) sm[wid] = m;
  __syncthreads();
  float M = fminf(fminf(sm[0], sm[1]), fminf(sm[2], sm[3]));
  float e = fexp2(-ALPHA_C * LOG2E * (v - M));
  float s = wred_sum(e);
  if (lane == 0) ss[wid] = s;
  __syncthreads();
  if (t == 0) {
    float S = ss[0] + ss[1] + ss[2] + ss[3];
    out[b] = M - flog2(S) * LN2 / ALPHA_C;
  }
}

extern "C" void kernel_launch(void* const* d_in, const int* in_sizes, int n_in,
                              void* d_out, int out_size, void* d_ws, size_t ws_size,
                              hipStream_t stream) {
  const float* positions = (const float*)d_in[0];
  const float* kde       = (const float*)d_in[1];
  const float* weight    = (const float*)d_in[2];
  const float* offs      = (const float*)d_in[3];
  const int*   atom_idxs = (const int*)d_in[4];
  const int*   gsizes    = (const int*)d_in[5];
  float* out = (float*)d_out;

  unsigned* gmin_u = (unsigned*)d_ws;                     // 512 KiB @ 0
  int* wl = (int*)d_ws + (size_t)NG * NB;                 // ~8 KiB @ 512 KiB
  float* tabG = (float*)((char*)d_ws + (1 << 20));        // 8 MiB @ 1 MiB

  prep_tab<<<dim3(WL_CAP), dim3(128), 0, stream>>>(kde, tabG);
  build_worklist<<<dim3(1 + FILL_BLOCKS), dim3(256), 0, stream>>>(
      gsizes, wl, (uint4*)gmin_u);
  stage1_kernel<<<dim3(WL_CAP), dim3(256), 0, stream>>>(
      positions, tabG, weight, offs, atom_idxs, wl, gmin_u);
  stage2_kernel<<<dim3(NB), dim3(256), 0, stream>>>(gmin_u, out);
}

// Round 11
// 50.707 us; speedup vs baseline: 1.2873x; 1.2873x over previous
//
#include <hip/hip_runtime.h>

#define NB 512
#define NATOMS 1024
#define NG 256
#define NL 8
#define NK 128

#define KBT 0.59616123f            // 0.0019872041 * 300
#define ALPHA_C 10.0f
#define LN2 0.6931471805599453f
#define LOG2E 1.4426950408889634f
#define INV2BW2 22.222221f         // 1/(2*0.15^2)
#define SCALE2 (INV2BW2 * LOG2E)   // log2-domain scale (~32.05)
#define LOG_NORM (-1.0170649f)     // log(128) + 3*log(2*pi*BW^2)

#define WL_CAP 2048                // max (g,l) pairs = NG*NL
#define FILL_BLOCKS 128            // 128*256*16B = 512 KiB = NG*NB*4B exactly

typedef _Float16 f16x8 __attribute__((ext_vector_type(8)));
typedef float f32x4 __attribute__((ext_vector_type(4)));

__device__ __forceinline__ float fexp2(float x) { return __builtin_amdgcn_exp2f(x); }
__device__ __forceinline__ float flog2(float x) { return __builtin_amdgcn_logf(x); }

// monotone float<->uint key (unsigned order == float order), for atomicMin
__device__ __forceinline__ unsigned fkey(float f) {
  unsigned u = __float_as_uint(f);
  return (u & 0x80000000u) ? ~u : (u | 0x80000000u);
}
__device__ __forceinline__ float funkey(unsigned k) {
  unsigned u = (k & 0x80000000u) ? (k ^ 0x80000000u) : ~k;
  return __uint_as_float(u);
}

__device__ __forceinline__ float wred_min(float v) {
#pragma unroll
  for (int m = 32; m >= 1; m >>= 1) v = fminf(v, __shfl_xor(v, m, 64));
  return v;
}
__device__ __forceinline__ float wred_sum(float v) {
#pragma unroll
  for (int m = 32; m >= 1; m >>= 1) v += __shfl_xor(v, m, 64);
  return v;
}

// ---------------------------------------------------------------------------
// A-operand prep: for each gl entry, build the 8 k-tile MFMA A-fragments.
// Contraction layout (c = 0..31), per dim q=0..5 with alpha = 2*SCALE2*mu:
//   c0-5 : A=alpha_hi[q]   (pairs B=x_hi[q])
//   c6-11: A=alpha_lo[q]   (pairs B=x_hi[q])
//   c12-17:A=alpha_hi[q]   (pairs B=x_lo[q])
//   c18-23:A=alpha_lo[q]   (pairs B=x_lo[q])
//   c24,25:A=z1,z2 (2-way fp16 split of -SCALE2*mu2), B=1
//   c26-31: zero
// Sum = 2S*(x.mu) - S*mu2 exactly to ~2^-21 rel; v2 = sum + (-S*x2) [added
// later as c2].  Lane l holds m=l&15 (k row) and c-chunk (l>>4)*8 + j.
// Stored as tabA[gl][kt][lane] : f16x8 -- stage1 reads 1KB/wave/tile,
// perfectly coalesced.  The same assumed c-map is used for A and B, so any
// k-permutation error in the assumed fragment layout cancels in A.B.
// ---------------------------------------------------------------------------
__global__ __launch_bounds__(64) void prep_tabA(
    const float* __restrict__ kde, f16x8* __restrict__ tabA) {
  const int gl = blockIdx.x;
  const int l = threadIdx.x;
  const int m = l & 15, chunk = l >> 4;
#pragma unroll
  for (int kt = 0; kt < 8; ++kt) {
    const int k = kt * 16 + m;
    const float* mp = kde + ((size_t)gl * NK + k) * 6;
    float mu2 = 0.0f;
    _Float16 ah[6], al[6];
#pragma unroll
    for (int q = 0; q < 6; ++q) {
      float mv = mp[q];
      mu2 += mv * mv;
      float a = (2.0f * SCALE2) * mv;
      _Float16 h = (_Float16)a;
      ah[q] = h;
      al[q] = (_Float16)(a - (float)h);
    }
    float z = -SCALE2 * mu2;
    _Float16 z1 = (_Float16)z;
    _Float16 z2 = (_Float16)(z - (float)z1);
    const _Float16 Z = (_Float16)0.0f;
    f16x8 out;
    if (chunk == 0)      out = (f16x8){ah[0],ah[1],ah[2],ah[3],ah[4],ah[5],al[0],al[1]};
    else if (chunk == 1) out = (f16x8){al[2],al[3],al[4],al[5],ah[0],ah[1],ah[2],ah[3]};
    else if (chunk == 2) out = (f16x8){ah[4],ah[5],al[0],al[1],al[2],al[3],al[4],al[5]};
    else                 out = (f16x8){z1,  z2,  Z,    Z,    Z,    Z,    Z,    Z   };
    tabA[((size_t)gl * 8 + kt) * 64 + l] = out;
  }
}

// Grid = 1 + FILL_BLOCKS.  Block 0: prefix-sum nl -> packed worklist of
// active (g,l) pairs (wl[WL_CAP] = count).  Blocks 1..: fill gmin_u keys.
__global__ __launch_bounds__(256) void build_worklist(
    const int* __restrict__ gsizes, int* __restrict__ wl,
    uint4* __restrict__ gmin_u4) {
  const int t = threadIdx.x;
  if (blockIdx.x != 0) {
    const unsigned F = 0xFFFFFFFFu;
    gmin_u4[(blockIdx.x - 1) * 256 + t] = make_uint4(F, F, F, F);
    return;
  }
  const int lane = t & 63, wid = t >> 6;
  int gs = gsizes[t];
  int nl = gs < 1 ? 1 : (gs > NL ? NL : gs);
  int x = nl;
#pragma unroll
  for (int m = 1; m < 64; m <<= 1) {
    int y = __shfl_up(x, m, 64);
    if (lane >= m) x += y;
  }
  __shared__ int wsum[4];
  if (lane == 63) wsum[wid] = x;
  __syncthreads();
  int off = 0;
  for (int i = 0; i < wid; ++i) off += wsum[i];
  int inc = off + x, exc = inc - nl;
  for (int j = 0; j < nl; ++j) wl[exc + j] = (t << 3) | j;   // entry == gl
  if (t == 255) wl[WL_CAP] = inc;
}

// Block = (worklist entry w = bid>>3, b-chunk bid&7).  Wave covers 16 b's
// (col = lane&15); 8 MFMAs (k-tiles) give lane 32 v2-values (its b, 32 k's).
// No LDS, no barriers, no per-k table reads: A-frags = 8 coalesced 1KB
// loads/wave.  LSE: 31-op in-register tree + 2 shfl_xor (max), same for sum.
__global__ __launch_bounds__(256) void stage1_kernel(
    const float* __restrict__ positions, const f16x8* __restrict__ tabA,
    const float* __restrict__ weight, const float* __restrict__ offs,
    const int* __restrict__ atom_idxs, const int* __restrict__ wl,
    unsigned* __restrict__ gmin_u) {
  const int count = wl[WL_CAP];
  const int w = blockIdx.x >> 3;
  if (w >= count) return;                  // contiguous inactive tail
  const int gl = wl[w];
  const int g = gl >> 3;

  const int t = threadIdx.x;
  const int lane = t & 63;
  const int bcol = lane & 15, chunk = lane >> 4;
  const int b = ((blockIdx.x & 7) << 6) + ((t >> 6) << 4) + bcol;

  // --- distances for my b (4 lanes per b compute redundantly) ---
  const int4 idx = *reinterpret_cast<const int4*>(atom_idxs + (gl << 2));
  const int ids[4] = {idx.x, idx.y, idx.z, idx.w};
  const float* pb = positions + (size_t)b * NATOMS * 3;
  float ax[4], ay[4], az[4];
#pragma unroll
  for (int j = 0; j < 4; ++j) {
    const float3 p = *reinterpret_cast<const float3*>(pb + ids[j] * 3);
    ax[j] = p.x; ay[j] = p.y; az[j] = p.z;
  }
  const int PI_[6] = {0, 0, 0, 1, 1, 2};
  const int PJ_[6] = {1, 2, 3, 2, 3, 3};
  float d[6]; float x2 = 0.0f;
#pragma unroll
  for (int q = 0; q < 6; ++q) {
    float dx = ax[PI_[q]] - ax[PJ_[q]];
    float dy = ay[PI_[q]] - ay[PJ_[q]];
    float dz = az[PI_[q]] - az[PJ_[q]];
    float dd = dx * dx + dy * dy + dz * dz + 1e-12f;
    d[q] = sqrtf(dd);
    x2 += d[q] * d[q];
  }
  const float c2 = -x2 * SCALE2;           // per-b constant (log2 domain)

  // --- B-fragment: 2-way fp16 split of dists, c-layout matching prep ---
  _Float16 xh[6], xl[6];
#pragma unroll
  for (int q = 0; q < 6; ++q) {
    _Float16 h = (_Float16)d[q];
    xh[q] = h;
    xl[q] = (_Float16)(d[q] - (float)h);
  }
  const _Float16 ONE = (_Float16)1.0f, Z = (_Float16)0.0f;
  f16x8 Bf;
  if (chunk == 0)      Bf = (f16x8){xh[0],xh[1],xh[2],xh[3],xh[4],xh[5],xh[0],xh[1]};
  else if (chunk == 1) Bf = (f16x8){xh[2],xh[3],xh[4],xh[5],xl[0],xl[1],xl[2],xl[3]};
  else if (chunk == 2) Bf = (f16x8){xl[4],xl[5],xl[0],xl[1],xl[2],xl[3],xl[4],xl[5]};
  else                 Bf = (f16x8){ONE,  ONE,  Z,    Z,    Z,    Z,    Z,    Z   };

  // --- A-fragments: 8 coalesced 1KB loads; 8 independent MFMAs ---
  const f16x8* tp = tabA + ((size_t)gl * 8) * 64 + lane;
  f16x8 Af[8];
#pragma unroll
  for (int kt = 0; kt < 8; ++kt) Af[kt] = tp[kt * 64];
  const f32x4 zz = {0.0f, 0.0f, 0.0f, 0.0f};
  f32x4 acc[8];
#pragma unroll
  for (int kt = 0; kt < 8; ++kt)
    acc[kt] = __builtin_amdgcn_mfma_f32_16x16x32_f16(Af[kt], Bf, zz, 0, 0, 0);

  // --- LSE over 128 k: 32 in-register + lanes {+16,+32} hold the rest ---
  float mkt[8];
#pragma unroll
  for (int kt = 0; kt < 8; ++kt)
    mkt[kt] = fmaxf(fmaxf(acc[kt][0], acc[kt][1]), fmaxf(acc[kt][2], acc[kt][3]));
  float mx = fmaxf(fmaxf(fmaxf(mkt[0], mkt[1]), fmaxf(mkt[2], mkt[3])),
                   fmaxf(fmaxf(mkt[4], mkt[5]), fmaxf(mkt[6], mkt[7])));
  mx = fmaxf(mx, __shfl_xor(mx, 16, 64));
  mx = fmaxf(mx, __shfl_xor(mx, 32, 64));

  float sa = 0.0f, sb = 0.0f;
#pragma unroll
  for (int kt = 0; kt < 8; ++kt) {
    sa += fexp2(acc[kt][0] - mx) + fexp2(acc[kt][1] - mx);
    sb += fexp2(acc[kt][2] - mx) + fexp2(acc[kt][3] - mx);
  }
  float s = sa + sb;
  s += __shfl_xor(s, 16, 64);
  s += __shfl_xor(s, 32, 64);

  if (chunk == 0) {
    float lse2 = c2 + mx + flog2(s);       // log2(sum_k exp(v_k))
    float logP = lse2 * LN2 - LOG_NORM;
    float scaled = -KBT * logP * weight[gl] + offs[gl];
    atomicMin(&gmin_u[g * NB + b], fkey(scaled));
  }
}

// One block per b: min over g, then logsumexp(-ALPHA*gmin) over g.
__global__ __launch_bounds__(256) void stage2_kernel(
    const unsigned* __restrict__ gmin_u, float* __restrict__ out) {
  const int b = blockIdx.x;
  const int t = threadIdx.x;
  const int lane = t & 63;
  const int wid = t >> 6;
  float v = funkey(gmin_u[t * NB + b]);
  __shared__ float sm[4], ss[4];
  float m = wred_min(v);
  if (lane == 0) sm[wid] = m;
  __syncthreads();
  float M = fminf(fminf(sm[0], sm[1]), fminf(sm[2], sm[3]));
  float e = fexp2(-ALPHA_C * LOG2E * (v - M));
  float s = wred_sum(e);
  if (lane == 0) ss[wid] = s;
  __syncthreads();
  if (t == 0) {
    float S = ss[0] + ss[1] + ss[2] + ss[3];
    out[b] = M - flog2(S) * LN2 / ALPHA_C;
  }
}

extern "C" void kernel_launch(void* const* d_in, const int* in_sizes, int n_in,
                              void* d_out, int out_size, void* d_ws, size_t ws_size,
                              hipStream_t stream) {
  const float* positions = (const float*)d_in[0];
  const float* kde       = (const float*)d_in[1];
  const float* weight    = (const float*)d_in[2];
  const float* offs      = (const float*)d_in[3];
  const int*   atom_idxs = (const int*)d_in[4];
  const int*   gsizes    = (const int*)d_in[5];
  float* out = (float*)d_out;

  unsigned* gmin_u = (unsigned*)d_ws;                     // 512 KiB @ 0
  int* wl = (int*)d_ws + (size_t)NG * NB;                 // ~8 KiB @ 512 KiB
  f16x8* tabA = (f16x8*)((char*)d_ws + (1 << 20));        // 16 MiB @ 1 MiB

  prep_tabA<<<dim3(WL_CAP), dim3(64), 0, stream>>>(kde, tabA);
  build_worklist<<<dim3(1 + FILL_BLOCKS), dim3(256), 0, stream>>>(
      gsizes, wl, (uint4*)gmin_u);
  stage1_kernel<<<dim3(WL_CAP * 8), dim3(256), 0, stream>>>(
      positions, tabA, weight, offs, atom_idxs, wl, gmin_u);
  stage2_kernel<<<dim3(NB), dim3(256), 0, stream>>>(gmin_u, out);
}

// Round 12
// 45.498 us; speedup vs baseline: 1.4347x; 1.1145x over previous
//
#include <hip/hip_runtime.h>

#define NB 512
#define NATOMS 1024
#define NG 256
#define NL 8
#define NK 128

#define KBT 0.59616123f            // 0.0019872041 * 300
#define ALPHA_C 10.0f
#define LN2 0.6931471805599453f
#define LOG2E 1.4426950408889634f
#define INV2BW2 22.222221f         // 1/(2*0.15^2)
#define SCALE2 (INV2BW2 * LOG2E)   // log2-domain scale (~32.05)
#define LOG_NORM (-1.0170649f)     // log(128) + 3*log(2*pi*BW^2)

#define WL_CAP 2048                // max (g,l) pairs = NG*NL
#define FILL_BLOCKS 128            // 128*256*16B = 512 KiB = NG*NB*4B exactly

typedef _Float16 f16x8 __attribute__((ext_vector_type(8)));
typedef float f32x4 __attribute__((ext_vector_type(4)));

__device__ __forceinline__ float fexp2(float x) { return __builtin_amdgcn_exp2f(x); }
__device__ __forceinline__ float flog2(float x) { return __builtin_amdgcn_logf(x); }

// monotone float<->uint key (unsigned order == float order), for atomicMin
__device__ __forceinline__ unsigned fkey(float f) {
  unsigned u = __float_as_uint(f);
  return (u & 0x80000000u) ? ~u : (u | 0x80000000u);
}
__device__ __forceinline__ float funkey(unsigned k) {
  unsigned u = (k & 0x80000000u) ? (k ^ 0x80000000u) : ~k;
  return __uint_as_float(u);
}

__device__ __forceinline__ float wred_min(float v) {
#pragma unroll
  for (int m = 32; m >= 1; m >>= 1) v = fminf(v, __shfl_xor(v, m, 64));
  return v;
}
__device__ __forceinline__ float wred_sum(float v) {
#pragma unroll
  for (int m = 32; m >= 1; m >>= 1) v += __shfl_xor(v, m, 64);
  return v;
}

// ---------------------------------------------------------------------------
// A-operand prep (unchanged from r10, absmax 0.0 verified): per gl, the 8
// k-tile MFMA A-fragments with 2-way fp16 splits.  Contraction c-layout:
//   c0-5: ah*xh  c6-11: al*xh  c12-17: ah*xl  c18-23: al*xl
//   c24,25: z1,z2 (split of -S*mu2) * 1     c26-31: 0
// ---------------------------------------------------------------------------
__global__ __launch_bounds__(64) void prep_tabA(
    const float* __restrict__ kde, f16x8* __restrict__ tabA) {
  const int gl = blockIdx.x;
  const int l = threadIdx.x;
  const int m = l & 15, chunk = l >> 4;
#pragma unroll
  for (int kt = 0; kt < 8; ++kt) {
    const int k = kt * 16 + m;
    const float* mp = kde + ((size_t)gl * NK + k) * 6;
    float mu2 = 0.0f;
    _Float16 ah[6], al[6];
#pragma unroll
    for (int q = 0; q < 6; ++q) {
      float mv = mp[q];
      mu2 += mv * mv;
      float a = (2.0f * SCALE2) * mv;
      _Float16 h = (_Float16)a;
      ah[q] = h;
      al[q] = (_Float16)(a - (float)h);
    }
    float z = -SCALE2 * mu2;
    _Float16 z1 = (_Float16)z;
    _Float16 z2 = (_Float16)(z - (float)z1);
    const _Float16 Z = (_Float16)0.0f;
    f16x8 out;
    if (chunk == 0)      out = (f16x8){ah[0],ah[1],ah[2],ah[3],ah[4],ah[5],al[0],al[1]};
    else if (chunk == 1) out = (f16x8){al[2],al[3],al[4],al[5],ah[0],ah[1],ah[2],ah[3]};
    else if (chunk == 2) out = (f16x8){ah[4],ah[5],al[0],al[1],al[2],al[3],al[4],al[5]};
    else                 out = (f16x8){z1,  z2,  Z,    Z,    Z,    Z,    Z,    Z   };
    tabA[((size_t)gl * 8 + kt) * 64 + l] = out;
  }
}

// Grid = 1 + FILL_BLOCKS.  Block 0: prefix-sum nl -> packed worklist of
// active (g,l) pairs (wl[WL_CAP] = count).  Blocks 1..: fill gmin_u keys.
__global__ __launch_bounds__(256) void build_worklist(
    const int* __restrict__ gsizes, int* __restrict__ wl,
    uint4* __restrict__ gmin_u4) {
  const int t = threadIdx.x;
  if (blockIdx.x != 0) {
    const unsigned F = 0xFFFFFFFFu;
    gmin_u4[(blockIdx.x - 1) * 256 + t] = make_uint4(F, F, F, F);
    return;
  }
  const int lane = t & 63, wid = t >> 6;
  int gs = gsizes[t];
  int nl = gs < 1 ? 1 : (gs > NL ? NL : gs);
  int x = nl;
#pragma unroll
  for (int m = 1; m < 64; m <<= 1) {
    int y = __shfl_up(x, m, 64);
    if (lane >= m) x += y;
  }
  __shared__ int wsum[4];
  if (lane == 63) wsum[wid] = x;
  __syncthreads();
  int off = 0;
  for (int i = 0; i < wid; ++i) off += wsum[i];
  int inc = off + x, exc = inc - nl;
  for (int j = 0; j < nl; ++j) wl[exc + j] = (t << 3) | j;   // entry == gl
  if (t == 255) wl[WL_CAP] = inc;
}

// Block = (worklist entry w = bid>>1, b-half = bid&1).  Each wave covers
// 64 b's: A-fragments (8 x f16x8, the gl's whole table) are loaded ONCE and
// reused across 4 b-group iterations of 16 b's each -- 4x fewer waves and
// 4x less A-traffic than r10 (the r10->r11 gap was per-wave fixed cost).
// Gathers for all 4 groups issue up front.  No LDS, no barriers.
__global__ __launch_bounds__(256) void stage1_kernel(
    const float* __restrict__ positions, const f16x8* __restrict__ tabA,
    const float* __restrict__ weight, const float* __restrict__ offs,
    const int* __restrict__ atom_idxs, const int* __restrict__ wl,
    unsigned* __restrict__ gmin_u) {
  const int count = wl[WL_CAP];
  const int w = blockIdx.x >> 1;
  if (w >= count) return;                  // contiguous inactive tail
  const int gl = wl[w];
  const int g = gl >> 3;
  const int half = blockIdx.x & 1;

  const int t = threadIdx.x;
  const int lane = t & 63;
  const int wid = t >> 6;
  const int bcol = lane & 15, chunk = lane >> 4;
  const int b0 = (half << 8) + (wid << 6) + bcol;   // + h*16

  // --- A-fragments: 8 coalesced 1KB loads, resident for the whole block ---
  const f16x8* tp = tabA + ((size_t)gl * 8) * 64 + lane;
  f16x8 Af[8];
#pragma unroll
  for (int kt = 0; kt < 8; ++kt) Af[kt] = tp[kt * 64];

  // --- gather + distances for my 4 b's (loads issued up front) ---
  const int4 idx = *reinterpret_cast<const int4*>(atom_idxs + (gl << 2));
  const int ids[4] = {idx.x, idx.y, idx.z, idx.w};
  const int PI_[6] = {0, 0, 0, 1, 1, 2};
  const int PJ_[6] = {1, 2, 3, 2, 3, 3};
  float d[4][6], c2[4];
#pragma unroll
  for (int h = 0; h < 4; ++h) {
    const int b = b0 + (h << 4);
    const float* pb = positions + (size_t)b * NATOMS * 3;
    float ax[4], ay[4], az[4];
#pragma unroll
    for (int j = 0; j < 4; ++j) {
      const float3 p = *reinterpret_cast<const float3*>(pb + ids[j] * 3);
      ax[j] = p.x; ay[j] = p.y; az[j] = p.z;
    }
    float x2 = 0.0f;
#pragma unroll
    for (int q = 0; q < 6; ++q) {
      float dx = ax[PI_[q]] - ax[PJ_[q]];
      float dy = ay[PI_[q]] - ay[PJ_[q]];
      float dz = az[PI_[q]] - az[PJ_[q]];
      float dd = dx * dx + dy * dy + dz * dz + 1e-12f;
      d[h][q] = sqrtf(dd);
      x2 += d[h][q] * d[h][q];
    }
    c2[h] = -x2 * SCALE2;                 // per-b constant (log2 domain)
  }

  const float wgt = weight[gl], off = offs[gl];
  const _Float16 ONE = (_Float16)1.0f, Z = (_Float16)0.0f;
  const f32x4 zz = {0.0f, 0.0f, 0.0f, 0.0f};

#pragma unroll
  for (int h = 0; h < 4; ++h) {
    // B-fragment: 2-way fp16 split of dists, c-layout matching prep
    _Float16 xh[6], xl[6];
#pragma unroll
    for (int q = 0; q < 6; ++q) {
      _Float16 hh = (_Float16)d[h][q];
      xh[q] = hh;
      xl[q] = (_Float16)(d[h][q] - (float)hh);
    }
    f16x8 Bf;
    if (chunk == 0)      Bf = (f16x8){xh[0],xh[1],xh[2],xh[3],xh[4],xh[5],xh[0],xh[1]};
    else if (chunk == 1) Bf = (f16x8){xh[2],xh[3],xh[4],xh[5],xl[0],xl[1],xl[2],xl[3]};
    else if (chunk == 2) Bf = (f16x8){xl[4],xl[5],xl[0],xl[1],xl[2],xl[3],xl[4],xl[5]};
    else                 Bf = (f16x8){ONE,  ONE,  Z,    Z,    Z,    Z,    Z,    Z   };

    f32x4 acc[8];
#pragma unroll
    for (int kt = 0; kt < 8; ++kt)
      acc[kt] = __builtin_amdgcn_mfma_f32_16x16x32_f16(Af[kt], Bf, zz, 0, 0, 0);

    // LSE over 128 k: 32 in-register; lanes {+16,+32} hold the other chunks
    float mkt[8];
#pragma unroll
    for (int kt = 0; kt < 8; ++kt)
      mkt[kt] = fmaxf(fmaxf(acc[kt][0], acc[kt][1]), fmaxf(acc[kt][2], acc[kt][3]));
    float mx = fmaxf(fmaxf(fmaxf(mkt[0], mkt[1]), fmaxf(mkt[2], mkt[3])),
                     fmaxf(fmaxf(mkt[4], mkt[5]), fmaxf(mkt[6], mkt[7])));
    mx = fmaxf(mx, __shfl_xor(mx, 16, 64));
    mx = fmaxf(mx, __shfl_xor(mx, 32, 64));

    float sa = 0.0f, sb = 0.0f;
#pragma unroll
    for (int kt = 0; kt < 8; ++kt) {
      sa += fexp2(acc[kt][0] - mx) + fexp2(acc[kt][1] - mx);
      sb += fexp2(acc[kt][2] - mx) + fexp2(acc[kt][3] - mx);
    }
    float s = sa + sb;
    s += __shfl_xor(s, 16, 64);
    s += __shfl_xor(s, 32, 64);

    if (chunk == 0) {
      float lse2 = c2[h] + mx + flog2(s);  // log2(sum_k exp(v_k))
      float logP = lse2 * LN2 - LOG_NORM;
      float scaled = -KBT * logP * wgt + off;
      atomicMin(&gmin_u[g * NB + b0 + (h << 4)], fkey(scaled));
    }
  }
}

// One block per b: min over g, then logsumexp(-ALPHA*gmin) over g.
__global__ __launch_bounds__(256) void stage2_kernel(
    const unsigned* __restrict__ gmin_u, float* __restrict__ out) {
  const int b = blockIdx.x;
  const int t = threadIdx.x;
  const int lane = t & 63;
  const int wid = t >> 6;
  float v = funkey(gmin_u[t * NB + b]);
  __shared__ float sm[4], ss[4];
  float m = wred_min(v);
  if (lane == 0) sm[wid] = m;
  __syncthreads();
  float M = fminf(fminf(sm[0], sm[1]), fminf(sm[2], sm[3]));
  float e = fexp2(-ALPHA_C * LOG2E * (v - M));
  float s = wred_sum(e);
  if (lane == 0) ss[wid] = s;
  __syncthreads();
  if (t == 0) {
    float S = ss[0] + ss[1] + ss[2] + ss[3];
    out[b] = M - flog2(S) * LN2 / ALPHA_C;
  }
}

extern "C" void kernel_launch(void* const* d_in, const int* in_sizes, int n_in,
                              void* d_out, int out_size, void* d_ws, size_t ws_size,
                              hipStream_t stream) {
  const float* positions = (const float*)d_in[0];
  const float* kde       = (const float*)d_in[1];
  const float* weight    = (const float*)d_in[2];
  const float* offs      = (const float*)d_in[3];
  const int*   atom_idxs = (const int*)d_in[4];
  const int*   gsizes    = (const int*)d_in[5];
  float* out = (float*)d_out;

  unsigned* gmin_u = (unsigned*)d_ws;                     // 512 KiB @ 0
  int* wl = (int*)d_ws + (size_t)NG * NB;                 // ~8 KiB @ 512 KiB
  f16x8* tabA = (f16x8*)((char*)d_ws + (1 << 20));        // 16 MiB @ 1 MiB

  prep_tabA<<<dim3(WL_CAP), dim3(64), 0, stream>>>(kde, tabA);
  build_worklist<<<dim3(1 + FILL_BLOCKS), dim3(256), 0, stream>>>(
      gsizes, wl, (uint4*)gmin_u);
  stage1_kernel<<<dim3(WL_CAP * 2), dim3(256), 0, stream>>>(
      positions, tabA, weight, offs, atom_idxs, wl, gmin_u);
  stage2_kernel<<<dim3(NB), dim3(256), 0, stream>>>(gmin_u, out);
}

// Round 13
// 39.323 us; speedup vs baseline: 1.6600x; 1.1570x over previous
//
#include <hip/hip_runtime.h>

#define NB 512
#define NATOMS 1024
#define NG 256
#define NL 8
#define NK 128

#define KBT 0.59616123f            // 0.0019872041 * 300
#define ALPHA_C 10.0f
#define LN2 0.6931471805599453f
#define LOG2E 1.4426950408889634f
#define INV2BW2 22.222221f         // 1/(2*0.15^2)
#define SCALE2 (INV2BW2 * LOG2E)   // log2-domain scale (~32.05)
#define LOG_NORM (-1.0170649f)     // log(128) + 3*log(2*pi*BW^2)

#define WL_CAP 2048                // max (g,l) pairs = NG*NL
#define FILL_BLOCKS 128            // 128*256*16B = 512 KiB = NG*NB*4B exactly

typedef _Float16 f16x8 __attribute__((ext_vector_type(8)));
typedef float f32x16 __attribute__((ext_vector_type(16)));

__device__ __forceinline__ float fexp2(float x) { return __builtin_amdgcn_exp2f(x); }
__device__ __forceinline__ float flog2(float x) { return __builtin_amdgcn_logf(x); }

// monotone float<->uint key (unsigned order == float order), for atomicMin
__device__ __forceinline__ unsigned fkey(float f) {
  unsigned u = __float_as_uint(f);
  return (u & 0x80000000u) ? ~u : (u | 0x80000000u);
}
__device__ __forceinline__ float funkey(unsigned k) {
  unsigned u = (k & 0x80000000u) ? (k ^ 0x80000000u) : ~k;
  return __uint_as_float(u);
}

__device__ __forceinline__ float wred_min(float v) {
#pragma unroll
  for (int m = 32; m >= 1; m >>= 1) v = fminf(v, __shfl_xor(v, m, 64));
  return v;
}
__device__ __forceinline__ float wred_sum(float v) {
#pragma unroll
  for (int m = 32; m >= 1; m >>= 1) v += __shfl_xor(v, m, 64);
  return v;
}

// ---------------------------------------------------------------------------
// Combined prep (one launch):
//   bid 0            : prefix-sum nl -> packed worklist (wl[WL_CAP] = count)
//   bid 1..128       : fill gmin_u keys with 0xFFFFFFFF (512 KiB)
//   bid 129..640     : A-fragment tables, 4 gl per block (t>>6), lane t&63
//
// Contraction c-layout (26 of 32 slots over TWO K=16 MFMAs), per dim q with
// alpha = 2*S*mu, z = -S*mu2 (2-way fp16 splits ah/al, z1/z2; B side xh/xl):
//   MFMA#0 lane-half0: c0-7  = {ah0..5,al0,al1} . {xh0..5,xh0,xh1}
//   MFMA#0 lane-half1: c8-15 = {al2..5,ah0..3}  . {xh2..5,xl0..3}
//   MFMA#1 lane-half0: c16-23= {ah4,ah5,al0..5} . {xl4,xl5,xl0..5}
//   MFMA#1 lane-half1: c24-31= {z1,z2,0...}     . {1,1,0...}
// Sum over both MFMAs = alpha.x + z exactly (verified absmax 0.0 in r10/r12
// with the identical chunk contents on the 16x16 shape).
// tabA[gl][kt][j][lane] (f16x8): row m = lane&31 -> k = kt*32+m, half = lane>>5.
// ---------------------------------------------------------------------------
__global__ __launch_bounds__(256) void prep_all(
    const float* __restrict__ kde, const int* __restrict__ gsizes,
    int* __restrict__ wl, uint4* __restrict__ gmin_u4,
    f16x8* __restrict__ tabA) {
  const int t = threadIdx.x;
  const int bid = blockIdx.x;

  if (bid == 0) {
    const int lane = t & 63, wid = t >> 6;
    int gs = gsizes[t];
    int nl = gs < 1 ? 1 : (gs > NL ? NL : gs);
    int x = nl;
#pragma unroll
    for (int m = 1; m < 64; m <<= 1) {
      int y = __shfl_up(x, m, 64);
      if (lane >= m) x += y;
    }
    __shared__ int wsum[4];
    if (lane == 63) wsum[wid] = x;
    __syncthreads();
    int off = 0;
    for (int i = 0; i < wid; ++i) off += wsum[i];
    int inc = off + x, exc = inc - nl;
    for (int j = 0; j < nl; ++j) wl[exc + j] = (t << 3) | j;   // entry == gl
    if (t == 255) wl[WL_CAP] = inc;
    return;
  }
  if (bid <= FILL_BLOCKS) {
    const unsigned F = 0xFFFFFFFFu;
    gmin_u4[(bid - 1) * 256 + t] = make_uint4(F, F, F, F);
    return;
  }

  const int gl = (bid - 129) * 4 + (t >> 6);
  const int l = t & 63;
  const int m = l & 31, h = l >> 5;
#pragma unroll
  for (int kt = 0; kt < 4; ++kt) {
    const int k = kt * 32 + m;
    const float* mp = kde + ((size_t)gl * NK + k) * 6;
    float mu2 = 0.0f;
    _Float16 ah[6], al[6];
#pragma unroll
    for (int q = 0; q < 6; ++q) {
      float mv = mp[q];
      mu2 += mv * mv;
      float a = (2.0f * SCALE2) * mv;
      _Float16 hh = (_Float16)a;
      ah[q] = hh;
      al[q] = (_Float16)(a - (float)hh);
    }
    float z = -SCALE2 * mu2;
    _Float16 z1 = (_Float16)z;
    _Float16 z2 = (_Float16)(z - (float)z1);
    const _Float16 Z = (_Float16)0.0f;
    // chunk patterns (same as r10/r12): h selects within each MFMA
    f16x8 j0 = (h == 0)
      ? (f16x8){ah[0],ah[1],ah[2],ah[3],ah[4],ah[5],al[0],al[1]}
      : (f16x8){al[2],al[3],al[4],al[5],ah[0],ah[1],ah[2],ah[3]};
    f16x8 j1 = (h == 0)
      ? (f16x8){ah[4],ah[5],al[0],al[1],al[2],al[3],al[4],al[5]}
      : (f16x8){z1,  z2,  Z,   Z,   Z,   Z,   Z,   Z   };
    const size_t base = ((size_t)gl * 4 + kt) * 2;
    tabA[(base + 0) * 64 + l] = j0;
    tabA[(base + 1) * 64 + l] = j1;
  }
}

// Block = (entry w = bid>>2, b-quarter bid&3).  Wave covers 32 b's
// (col = lane&31, ONE b per lane -- no redundant distance work).  Per k-tile
// (32 k's), two accumulating 32x32x16 MFMAs; lane ends with 64 of its b's
// 128 k-values IN REGISTERS (16 regs x 4 tiles), partner lane^32 has the
// rest -> the whole 128-k LSE costs exactly 2 cross-lane shuffles (r12 had
// 16 in 4 serial chains -- the identified stall).  No LDS, no barriers.
__global__ __launch_bounds__(256) void stage1_kernel(
    const float* __restrict__ positions, const f16x8* __restrict__ tabA,
    const float* __restrict__ weight, const float* __restrict__ offs,
    const int* __restrict__ atom_idxs, const int* __restrict__ wl,
    unsigned* __restrict__ gmin_u) {
  const int count = wl[WL_CAP];
  const int w = blockIdx.x >> 2;
  if (w >= count) return;                  // contiguous inactive tail
  const int gl = wl[w];
  const int g = gl >> 3;

  const int t = threadIdx.x;
  const int lane = t & 63;
  const int col = lane & 31, h = lane >> 5;
  const int b = ((blockIdx.x & 3) << 7) + ((t >> 6) << 5) + col;

  // --- distances for my b (1 lane = 1 b; lane^32 duplicates) ---
  const int4 idx = *reinterpret_cast<const int4*>(atom_idxs + (gl << 2));
  const int ids[4] = {idx.x, idx.y, idx.z, idx.w};
  const float* pb = positions + (size_t)b * NATOMS * 3;
  float ax[4], ay[4], az[4];
#pragma unroll
  for (int j = 0; j < 4; ++j) {
    const float3 p = *reinterpret_cast<const float3*>(pb + ids[j] * 3);
    ax[j] = p.x; ay[j] = p.y; az[j] = p.z;
  }
  const int PI_[6] = {0, 0, 0, 1, 1, 2};
  const int PJ_[6] = {1, 2, 3, 2, 3, 3};
  float d[6]; float x2 = 0.0f;
#pragma unroll
  for (int q = 0; q < 6; ++q) {
    float dx = ax[PI_[q]] - ax[PJ_[q]];
    float dy = ay[PI_[q]] - ay[PJ_[q]];
    float dz = az[PI_[q]] - az[PJ_[q]];
    float dd = dx * dx + dy * dy + dz * dz + 1e-12f;
    d[q] = sqrtf(dd);
    x2 += d[q] * d[q];
  }
  const float c2 = -x2 * SCALE2;           // per-b constant (log2 domain)

  // --- B-fragments: 2-way fp16 split, chunk by lane-half (matches prep) ---
  _Float16 xh[6], xl[6];
#pragma unroll
  for (int q = 0; q < 6; ++q) {
    _Float16 hh = (_Float16)d[q];
    xh[q] = hh;
    xl[q] = (_Float16)(d[q] - (float)hh);
  }
  const _Float16 ONE = (_Float16)1.0f, Z = (_Float16)0.0f;
  f16x8 Bf0 = (h == 0)
    ? (f16x8){xh[0],xh[1],xh[2],xh[3],xh[4],xh[5],xh[0],xh[1]}
    : (f16x8){xh[2],xh[3],xh[4],xh[5],xl[0],xl[1],xl[2],xl[3]};
  f16x8 Bf1 = (h == 0)
    ? (f16x8){xl[4],xl[5],xl[0],xl[1],xl[2],xl[3],xl[4],xl[5]}
    : (f16x8){ONE,  ONE,  Z,   Z,   Z,   Z,   Z,   Z   };

  // --- 4 k-tiles x 2 accumulating MFMAs; A-frags coalesced 1KB loads ---
  const f16x8* tp = tabA + (size_t)gl * 8 * 64 + lane;
  const f32x16 zz = {0.0f};
  f32x16 acc[4];
#pragma unroll
  for (int kt = 0; kt < 4; ++kt) {
    f16x8 A0 = tp[(kt * 2 + 0) * 64];
    f16x8 A1 = tp[(kt * 2 + 1) * 64];
    acc[kt] = __builtin_amdgcn_mfma_f32_32x32x16_f16(
        A1, Bf1, __builtin_amdgcn_mfma_f32_32x32x16_f16(A0, Bf0, zz, 0, 0, 0),
        0, 0, 0);
  }

  // --- LSE over 128 k: 64 in registers + partner lane (1 shfl each) ---
  float mkt[4];
#pragma unroll
  for (int kt = 0; kt < 4; ++kt) {
    float m0 = fmaxf(fmaxf(acc[kt][0], acc[kt][1]), fmaxf(acc[kt][2], acc[kt][3]));
    float m1 = fmaxf(fmaxf(acc[kt][4], acc[kt][5]), fmaxf(acc[kt][6], acc[kt][7]));
    float m2 = fmaxf(fmaxf(acc[kt][8], acc[kt][9]), fmaxf(acc[kt][10], acc[kt][11]));
    float m3 = fmaxf(fmaxf(acc[kt][12], acc[kt][13]), fmaxf(acc[kt][14], acc[kt][15]));
    mkt[kt] = fmaxf(fmaxf(m0, m1), fmaxf(m2, m3));
  }
  float mx = fmaxf(fmaxf(mkt[0], mkt[1]), fmaxf(mkt[2], mkt[3]));
  mx = fmaxf(mx, __shfl_xor(mx, 32, 64));

  float s0 = 0.0f, s1 = 0.0f, s2 = 0.0f, s3 = 0.0f;
#pragma unroll
  for (int kt = 0; kt < 4; ++kt) {
    s0 += fexp2(acc[kt][0] - mx)  + fexp2(acc[kt][1] - mx)
        + fexp2(acc[kt][2] - mx)  + fexp2(acc[kt][3] - mx);
    s1 += fexp2(acc[kt][4] - mx)  + fexp2(acc[kt][5] - mx)
        + fexp2(acc[kt][6] - mx)  + fexp2(acc[kt][7] - mx);
    s2 += fexp2(acc[kt][8] - mx)  + fexp2(acc[kt][9] - mx)
        + fexp2(acc[kt][10] - mx) + fexp2(acc[kt][11] - mx);
    s3 += fexp2(acc[kt][12] - mx) + fexp2(acc[kt][13] - mx)
        + fexp2(acc[kt][14] - mx) + fexp2(acc[kt][15] - mx);
  }
  float s = (s0 + s1) + (s2 + s3);
  s += __shfl_xor(s, 32, 64);

  if (h == 0) {
    float lse2 = c2 + mx + flog2(s);       // log2(sum_k exp(v_k))
    float logP = lse2 * LN2 - LOG_NORM;
    float scaled = -KBT * logP * weight[gl] + offs[gl];
    atomicMin(&gmin_u[g * NB + b], fkey(scaled));
  }
}

// One block per b: min over g, then logsumexp(-ALPHA*gmin) over g.
__global__ __launch_bounds__(256) void stage2_kernel(
    const unsigned* __restrict__ gmin_u, float* __restrict__ out) {
  const int b = blockIdx.x;
  const int t = threadIdx.x;
  const int lane = t & 63;
  const int wid = t >> 6;
  float v = funkey(gmin_u[t * NB + b]);
  __shared__ float sm[4], ss[4];
  float m = wred_min(v);
  if (lane == 0) sm[wid] = m;
  __syncthreads();
  float M = fminf(fminf(sm[0], sm[1]), fminf(sm[2], sm[3]));
  float e = fexp2(-ALPHA_C * LOG2E * (v - M));
  float s = wred_sum(e);
  if (lane == 0) ss[wid] = s;
  __syncthreads();
  if (t == 0) {
    float S = ss[0] + ss[1] + ss[2] + ss[3];
    out[b] = M - flog2(S) * LN2 / ALPHA_C;
  }
}

extern "C" void kernel_launch(void* const* d_in, const int* in_sizes, int n_in,
                              void* d_out, int out_size, void* d_ws, size_t ws_size,
                              hipStream_t stream) {
  const float* positions = (const float*)d_in[0];
  const float* kde       = (const float*)d_in[1];
  const float* weight    = (const float*)d_in[2];
  const float* offs      = (const float*)d_in[3];
  const int*   atom_idxs = (const int*)d_in[4];
  const int*   gsizes    = (const int*)d_in[5];
  float* out = (float*)d_out;

  unsigned* gmin_u = (unsigned*)d_ws;                     // 512 KiB @ 0
  int* wl = (int*)d_ws + (size_t)NG * NB;                 // ~8 KiB @ 512 KiB
  f16x8* tabA = (f16x8*)((char*)d_ws + (1 << 20));        // 16 MiB @ 1 MiB

  prep_all<<<dim3(1 + FILL_BLOCKS + 512), dim3(256), 0, stream>>>(
      kde, gsizes, wl, (uint4*)gmin_u, tabA);
  stage1_kernel<<<dim3(WL_CAP * 4), dim3(256), 0, stream>>>(
      positions, tabA, weight, offs, atom_idxs, wl, gmin_u);
  stage2_kernel<<<dim3(NB), dim3(256), 0, stream>>>(gmin_u, out);
}

// Round 14
// 35.849 us; speedup vs baseline: 1.8209x; 1.0969x over previous
//
#include <hip/hip_runtime.h>

#define NB 512
#define NATOMS 1024
#define NG 256
#define NL 8
#define NK 128

#define KBT 0.59616123f            // 0.0019872041 * 300
#define ALPHA_C 10.0f
#define LN2 0.6931471805599453f
#define LOG2E 1.4426950408889634f
#define INV2BW2 22.222221f         // 1/(2*0.15^2)
#define SCALE2 (INV2BW2 * LOG2E)   // log2-domain scale (~32.05)
#define LOG_NORM (-1.0170649f)     // log(128) + 3*log(2*pi*BW^2)

#define WL_CAP 2048                // max (g,l) pairs = NG*NL
#define FILL_BLOCKS 128            // 128*256*16B = 512 KiB = NG*NB*4B exactly

typedef _Float16 f16x8 __attribute__((ext_vector_type(8)));
typedef float f32x16 __attribute__((ext_vector_type(16)));

__device__ __forceinline__ float fexp2(float x) { return __builtin_amdgcn_exp2f(x); }
__device__ __forceinline__ float flog2(float x) { return __builtin_amdgcn_logf(x); }

// monotone float<->uint key (unsigned order == float order), for atomicMin
__device__ __forceinline__ unsigned fkey(float f) {
  unsigned u = __float_as_uint(f);
  return (u & 0x80000000u) ? ~u : (u | 0x80000000u);
}
__device__ __forceinline__ float funkey(unsigned k) {
  unsigned u = (k & 0x80000000u) ? (k ^ 0x80000000u) : ~k;
  return __uint_as_float(u);
}

__device__ __forceinline__ float wred_min(float v) {
#pragma unroll
  for (int m = 32; m >= 1; m >>= 1) v = fminf(v, __shfl_xor(v, m, 64));
  return v;
}
__device__ __forceinline__ float wred_sum(float v) {
#pragma unroll
  for (int m = 32; m >= 1; m >>= 1) v += __shfl_xor(v, m, 64);
  return v;
}

// Grid = 1 + FILL_BLOCKS.  Block 0: prefix-sum nl -> packed worklist of
// active (g,l) pairs (wl[WL_CAP] = count).  Blocks 1..: fill gmin_u keys.
__global__ __launch_bounds__(256) void prep_small(
    const int* __restrict__ gsizes, int* __restrict__ wl,
    uint4* __restrict__ gmin_u4) {
  const int t = threadIdx.x;
  if (blockIdx.x != 0) {
    const unsigned F = 0xFFFFFFFFu;
    gmin_u4[(blockIdx.x - 1) * 256 + t] = make_uint4(F, F, F, F);
    return;
  }
  const int lane = t & 63, wid = t >> 6;
  int gs = gsizes[t];
  int nl = gs < 1 ? 1 : (gs > NL ? NL : gs);
  int x = nl;
#pragma unroll
  for (int m = 1; m < 64; m <<= 1) {
    int y = __shfl_up(x, m, 64);
    if (lane >= m) x += y;
  }
  __shared__ int wsum[4];
  if (lane == 63) wsum[wid] = x;
  __syncthreads();
  int off = 0;
  for (int i = 0; i < wid; ++i) off += wsum[i];
  int inc = off + x, exc = inc - nl;
  for (int j = 0; j < nl; ++j) wl[exc + j] = (t << 3) | j;   // entry == gl
  if (t == 255) wl[WL_CAP] = inc;
}

// ---------------------------------------------------------------------------
// stage1: block = (worklist entry w = bid>>2, b-quarter bid&3).  The block
// BUILDS its gl's 8KB A-fragment table in LDS (threads 0..127, one k each;
// math bit-identical to r13's verified prep -- absmax 0.0), then runs the
// r13 32x32x16 two-MFMA contraction with A-frags from ds_read_b128.
// Deletes: 512-block prep, 16MB tabA write, 118MB re-read, one launch gap;
// frees 32 resident VGPRs (Af loaded per-tile from LDS).
//
// Contraction c-layout per dim q, alpha = 2*S*mu, z = -S*mu2 (fp16 splits):
//   MFMA#0 h0: {ah0..5,al0,al1}.{xh0..5,xh0,xh1}
//   MFMA#0 h1: {al2..5,ah0..3}.{xh2..5,xl0..3}
//   MFMA#1 h0: {ah4,ah5,al0..5}.{xl4,xl5,xl0..5}
//   MFMA#1 h1: {z1,z2,0..}.{1,1,0..}
// C layout (m74/m101): col=lane&31 (b), lane holds 64 of its b's 128 k's,
// partner lane^32 the rest -> LSE = register tree + exactly 2 shuffles.
// ---------------------------------------------------------------------------
__global__ __launch_bounds__(256) void stage1_kernel(
    const float* __restrict__ positions, const float* __restrict__ kde,
    const float* __restrict__ weight, const float* __restrict__ offs,
    const int* __restrict__ atom_idxs, const int* __restrict__ wl,
    unsigned* __restrict__ gmin_u) {
  const int count = wl[WL_CAP];
  const int w = blockIdx.x >> 2;
  if (w >= count) return;                  // contiguous inactive tail
  const int gl = wl[w];
  const int g = gl >> 3;

  const int t = threadIdx.x;
  const int lane = t & 63;
  const int col = lane & 31, h = lane >> 5;
  const int b = ((blockIdx.x & 3) << 7) + ((t >> 6) << 5) + col;

  __shared__ f16x8 tabL[8][64];            // [kt*2+j][lane], 8 KiB

  // --- issue my b's position gather first (hides under the table build) ---
  const int4 idx = *reinterpret_cast<const int4*>(atom_idxs + (gl << 2));
  const int ids[4] = {idx.x, idx.y, idx.z, idx.w};
  const float* pb = positions + (size_t)b * NATOMS * 3;
  float ax[4], ay[4], az[4];
#pragma unroll
  for (int j = 0; j < 4; ++j) {
    const float3 p = *reinterpret_cast<const float3*>(pb + ids[j] * 3);
    ax[j] = p.x; ay[j] = p.y; az[j] = p.z;
  }

  // --- build the fragment table: thread k (0..127) fills 4 f16x8 slots ---
  if (t < NK) {
    const float* mp = kde + ((size_t)gl * NK + t) * 6;
    float mu2 = 0.0f;
    _Float16 ah[6], al[6];
#pragma unroll
    for (int q = 0; q < 6; ++q) {
      float mv = mp[q];
      mu2 += mv * mv;
      float a = (2.0f * SCALE2) * mv;
      _Float16 hh = (_Float16)a;
      ah[q] = hh;
      al[q] = (_Float16)(a - (float)hh);
    }
    float z = -SCALE2 * mu2;
    _Float16 z1 = (_Float16)z;
    _Float16 z2 = (_Float16)(z - (float)z1);
    const _Float16 Z = (_Float16)0.0f;
    const int kt = t >> 5, m = t & 31;
    tabL[kt * 2 + 0][m]      = (f16x8){ah[0],ah[1],ah[2],ah[3],ah[4],ah[5],al[0],al[1]};
    tabL[kt * 2 + 0][m + 32] = (f16x8){al[2],al[3],al[4],al[5],ah[0],ah[1],ah[2],ah[3]};
    tabL[kt * 2 + 1][m]      = (f16x8){ah[4],ah[5],al[0],al[1],al[2],al[3],al[4],al[5]};
    tabL[kt * 2 + 1][m + 32] = (f16x8){z1,  z2,  Z,   Z,   Z,   Z,   Z,   Z   };
  }

  // --- distances + B-fragments (independent of LDS; overlaps build) ---
  const int PI_[6] = {0, 0, 0, 1, 1, 2};
  const int PJ_[6] = {1, 2, 3, 2, 3, 3};
  float d[6]; float x2 = 0.0f;
#pragma unroll
  for (int q = 0; q < 6; ++q) {
    float dx = ax[PI_[q]] - ax[PJ_[q]];
    float dy = ay[PI_[q]] - ay[PJ_[q]];
    float dz = az[PI_[q]] - az[PJ_[q]];
    float dd = dx * dx + dy * dy + dz * dz + 1e-12f;
    d[q] = sqrtf(dd);
    x2 += d[q] * d[q];
  }
  const float c2 = -x2 * SCALE2;           // per-b constant (log2 domain)

  _Float16 xh[6], xl[6];
#pragma unroll
  for (int q = 0; q < 6; ++q) {
    _Float16 hh = (_Float16)d[q];
    xh[q] = hh;
    xl[q] = (_Float16)(d[q] - (float)hh);
  }
  const _Float16 ONE = (_Float16)1.0f, Z = (_Float16)0.0f;
  f16x8 Bf0 = (h == 0)
    ? (f16x8){xh[0],xh[1],xh[2],xh[3],xh[4],xh[5],xh[0],xh[1]}
    : (f16x8){xh[2],xh[3],xh[4],xh[5],xl[0],xl[1],xl[2],xl[3]};
  f16x8 Bf1 = (h == 0)
    ? (f16x8){xl[4],xl[5],xl[0],xl[1],xl[2],xl[3],xl[4],xl[5]}
    : (f16x8){ONE,  ONE,  Z,   Z,   Z,   Z,   Z,   Z   };

  __syncthreads();

  // --- 4 k-tiles x 2 accumulating MFMAs; A-frags from LDS per tile ---
  const f32x16 zz = {0.0f};
  f32x16 acc[4];
#pragma unroll
  for (int kt = 0; kt < 4; ++kt) {
    f16x8 A0 = tabL[kt * 2 + 0][lane];
    f16x8 A1 = tabL[kt * 2 + 1][lane];
    acc[kt] = __builtin_amdgcn_mfma_f32_32x32x16_f16(
        A1, Bf1, __builtin_amdgcn_mfma_f32_32x32x16_f16(A0, Bf0, zz, 0, 0, 0),
        0, 0, 0);
  }

  // --- LSE over 128 k: 64 in registers + partner lane (1 shfl each) ---
  float mkt[4];
#pragma unroll
  for (int kt = 0; kt < 4; ++kt) {
    float m0 = fmaxf(fmaxf(acc[kt][0], acc[kt][1]), fmaxf(acc[kt][2], acc[kt][3]));
    float m1 = fmaxf(fmaxf(acc[kt][4], acc[kt][5]), fmaxf(acc[kt][6], acc[kt][7]));
    float m2 = fmaxf(fmaxf(acc[kt][8], acc[kt][9]), fmaxf(acc[kt][10], acc[kt][11]));
    float m3 = fmaxf(fmaxf(acc[kt][12], acc[kt][13]), fmaxf(acc[kt][14], acc[kt][15]));
    mkt[kt] = fmaxf(fmaxf(m0, m1), fmaxf(m2, m3));
  }
  float mx = fmaxf(fmaxf(mkt[0], mkt[1]), fmaxf(mkt[2], mkt[3]));
  mx = fmaxf(mx, __shfl_xor(mx, 32, 64));

  float s0 = 0.0f, s1 = 0.0f, s2 = 0.0f, s3 = 0.0f;
#pragma unroll
  for (int kt = 0; kt < 4; ++kt) {
    s0 += fexp2(acc[kt][0] - mx)  + fexp2(acc[kt][1] - mx)
        + fexp2(acc[kt][2] - mx)  + fexp2(acc[kt][3] - mx);
    s1 += fexp2(acc[kt][4] - mx)  + fexp2(acc[kt][5] - mx)
        + fexp2(acc[kt][6] - mx)  + fexp2(acc[kt][7] - mx);
    s2 += fexp2(acc[kt][8] - mx)  + fexp2(acc[kt][9] - mx)
        + fexp2(acc[kt][10] - mx) + fexp2(acc[kt][11] - mx);
    s3 += fexp2(acc[kt][12] - mx) + fexp2(acc[kt][13] - mx)
        + fexp2(acc[kt][14] - mx) + fexp2(acc[kt][15] - mx);
  }
  float s = (s0 + s1) + (s2 + s3);
  s += __shfl_xor(s, 32, 64);

  if (h == 0) {
    float lse2 = c2 + mx + flog2(s);       // log2(sum_k exp(v_k))
    float logP = lse2 * LN2 - LOG_NORM;
    float scaled = -KBT * logP * weight[gl] + offs[gl];
    atomicMin(&gmin_u[g * NB + b], fkey(scaled));
  }
}

// One block per b: min over g, then logsumexp(-ALPHA*gmin) over g.
__global__ __launch_bounds__(256) void stage2_kernel(
    const unsigned* __restrict__ gmin_u, float* __restrict__ out) {
  const int b = blockIdx.x;
  const int t = threadIdx.x;
  const int lane = t & 63;
  const int wid = t >> 6;
  float v = funkey(gmin_u[t * NB + b]);
  __shared__ float sm[4], ss[4];
  float m = wred_min(v);
  if (lane == 0) sm[wid] = m;
  __syncthreads();
  float M = fminf(fminf(sm[0], sm[1]), fminf(sm[2], sm[3]));
  float e = fexp2(-ALPHA_C * LOG2E * (v - M));
  float s = wred_sum(e);
  if (lane == 0) ss[wid] = s;
  __syncthreads();
  if (t == 0) {
    float S = ss[0] + ss[1] + ss[2] + ss[3];
    out[b] = M - flog2(S) * LN2 / ALPHA_C;
  }
}

extern "C" void kernel_launch(void* const* d_in, const int* in_sizes, int n_in,
                              void* d_out, int out_size, void* d_ws, size_t ws_size,
                              hipStream_t stream) {
  const float* positions = (const float*)d_in[0];
  const float* kde       = (const float*)d_in[1];
  const float* weight    = (const float*)d_in[2];
  const float* offs      = (const float*)d_in[3];
  const int*   atom_idxs = (const int*)d_in[4];
  const int*   gsizes    = (const int*)d_in[5];
  float* out = (float*)d_out;

  unsigned* gmin_u = (unsigned*)d_ws;                     // 512 KiB @ 0
  int* wl = (int*)d_ws + (size_t)NG * NB;                 // ~8 KiB @ 512 KiB

  prep_small<<<dim3(1 + FILL_BLOCKS), dim3(256), 0, stream>>>(
      gsizes, wl, (uint4*)gmin_u);
  stage1_kernel<<<dim3(WL_CAP * 4), dim3(256), 0, stream>>>(
      positions, kde, weight, offs, atom_idxs, wl, gmin_u);
  stage2_kernel<<<dim3(NB), dim3(256), 0, stream>>>(gmin_u, out);
}